// Round 1
// baseline (743.155 us; speedup 1.0000x reference)
//
#include <hip/hip_runtime.h>
#include <hip/hip_bf16.h>

#define DEV __device__ __forceinline__

// ---------- helpers ----------
DEV float wave_sum(float v) {
#pragma unroll
    for (int off = 1; off < 64; off <<= 1) v += __shfl_xor(v, off, 64);
    return v;
}
DEV float bcast_lane(float v, int srcLane) {
    return __uint_as_float(__builtin_amdgcn_readlane(__float_as_uint(v), srcLane));
}
DEV float bf2f(unsigned short h) { return __uint_as_float(((unsigned)h) << 16); }
DEV unsigned short f2bf(float f) {
    unsigned u = __float_as_uint(f);
    unsigned r = u + 0x7fffu + ((u >> 16) & 1u);
    return (unsigned short)(r >> 16);
}
DEV void unpack8(uint4 a, float* o) {
    o[0] = __uint_as_float((a.x & 0xffffu) << 16);
    o[1] = __uint_as_float(a.x & 0xffff0000u);
    o[2] = __uint_as_float((a.y & 0xffffu) << 16);
    o[3] = __uint_as_float(a.y & 0xffff0000u);
    o[4] = __uint_as_float((a.z & 0xffffu) << 16);
    o[5] = __uint_as_float(a.z & 0xffff0000u);
    o[6] = __uint_as_float((a.w & 0xffffu) << 16);
    o[7] = __uint_as_float(a.w & 0xffff0000u);
}

// ---------- K1: LN + 128x128 projection (q or k/v), bf16 output ----------
// 1 wave per block, 8 tokens per block. Grid must be nTokens/8 (exact).
__global__ __launch_bounds__(64) void ln_proj_kernel(
    const float* __restrict__ src, const float* __restrict__ ln_g, const float* __restrict__ ln_b,
    const float* __restrict__ W, const float* __restrict__ bias,
    const float* __restrict__ head_gate, unsigned short* __restrict__ dst, int isQ)
{
    const int lane = threadIdx.x;
    const int t0 = blockIdx.x * 8;

    float xlo[8], xhi[8];
#pragma unroll
    for (int t = 0; t < 8; ++t) {
        int tok = t0 + t;
        int so;
        if (isQ) {
            // dest (b, l=Xi*10+Yi, qn=nn*100+wA*10+wB), src (b,nn,Xi,Yi,wA,wB)
            int b = tok / 60000, rem = tok % 60000;
            int l = rem / 600, qn = rem % 600;
            int Xi = l / 10, Yi = l % 10;
            int nn = qn / 100, wA = (qn / 10) % 10, wB = qn % 10;
            so = ((((b * 6 + nn) * 10 + Xi) * 10 + Yi) * 10 + wA) * 10 + wB;
        } else {
            // dest (b, l, kn=nn*16+wA*4+wB), src (b,nn,Xi,Yi,wA,wB) with w1=w2=4
            int b = tok / 9600, rem = tok % 9600;
            int l = rem / 96, kn = rem % 96;
            int Xi = l / 10, Yi = l % 10;
            int nn = kn / 16, wA = (kn / 4) % 4, wB = kn % 4;
            so = ((((b * 6 + nn) * 10 + Xi) * 10 + Yi) * 4 + wA) * 4 + wB;
        }
        const float* p = src + (long)so * 128;
        xlo[t] = p[lane];
        xhi[t] = p[64 + lane];
    }

    const float g0 = ln_g[lane], g1 = ln_g[64 + lane];
    const float e0 = ln_b[lane], e1 = ln_b[64 + lane];
#pragma unroll
    for (int t = 0; t < 8; ++t) {
        float s  = wave_sum(xlo[t] + xhi[t]);
        float s2 = wave_sum(xlo[t] * xlo[t] + xhi[t] * xhi[t]);
        float mean = s * (1.f / 128.f);
        float var  = s2 * (1.f / 128.f) - mean * mean;
        float rs = rsqrtf(var + 1e-5f);
        xlo[t] = (xlo[t] - mean) * rs * g0 + e0;
        xhi[t] = (xhi[t] - mean) * rs * g1 + e1;
    }

    float acc0[8], acc1[8];
    const float b0 = bias[lane], b1 = bias[64 + lane];
#pragma unroll
    for (int t = 0; t < 8; ++t) { acc0[t] = b0; acc1[t] = b1; }

    for (int k = 0; k < 64; ++k) {
        float w0 = W[k * 128 + lane];
        float w1 = W[k * 128 + 64 + lane];
#pragma unroll
        for (int t = 0; t < 8; ++t) {
            float xk = bcast_lane(xlo[t], k);
            acc0[t] = fmaf(xk, w0, acc0[t]);
            acc1[t] = fmaf(xk, w1, acc1[t]);
        }
    }
    for (int k = 0; k < 64; ++k) {
        float w0 = W[(64 + k) * 128 + lane];
        float w1 = W[(64 + k) * 128 + 64 + lane];
#pragma unroll
        for (int t = 0; t < 8; ++t) {
            float xk = bcast_lane(xhi[t], k);
            acc0[t] = fmaf(xk, w0, acc0[t]);
            acc1[t] = fmaf(xk, w1, acc1[t]);
        }
    }

    if (isQ) {
        const float scale = 0.17677669529663687f; // 32^-0.5
        float sg0 = scale * head_gate[lane >> 5];
        float sg1 = scale * head_gate[2 + (lane >> 5)];
#pragma unroll
        for (int t = 0; t < 8; ++t) { acc0[t] *= sg0; acc1[t] *= sg1; }
    }

#pragma unroll
    for (int t = 0; t < 8; ++t) {
        long o = (long)(t0 + t) * 128;
        dst[o + lane] = f2bf(acc0[t]);
        dst[o + 64 + lane] = f2bf(acc1[t]);
    }
}

// ---------- K2: windowed attention per (b,l,head); accumulates mean over n ----------
// grid = 400*4 = 1600 blocks of 256 threads. qh/kh/vh bf16, out amean bf16.
__global__ __launch_bounds__(256) void attn_kernel(
    const unsigned short* __restrict__ qh, const unsigned short* __restrict__ kh,
    const unsigned short* __restrict__ vh, unsigned short* __restrict__ am)
{
    __shared__ float khs[96][32];
    __shared__ float vhs[96][32];
    __shared__ float ams[100][32];

    const int tid = threadIdx.x;
    const int blk = blockIdx.x;      // (b*100+l)*4 + m
    const int m  = blk & 3;
    const int bl = blk >> 2;

    for (int i = tid; i < 3200; i += 256) (&ams[0][0])[i] = 0.f;

    const long kvBase = (long)bl * 12288 + m * 32;   // elements: (bl*96)*128 + m*32
    for (int i = tid; i < 384; i += 256) {
        int kt = i >> 2, j = i & 3;
        const uint4* kp = (const uint4*)(kh + kvBase + kt * 128);
        const uint4* vp = (const uint4*)(vh + kvBase + kt * 128);
        uint4 a = kp[j], b = vp[j];
        unpack8(a, &khs[kt][j * 8]);
        unpack8(b, &vhs[kt][j * 8]);
    }
    __syncthreads();

    const long qBase = (long)bl * 76800 + m * 32;    // (bl*600)*128 + m*32
    for (int pass = 0; pass < 2; ++pass) {
        int qA = pass * 256 + tid;                   // pair (qA, qA+300)
        if (qA < 300) {
            int qB = qA + 300;
            float qa[32], qb[32];
            const uint4* pa = (const uint4*)(qh + qBase + (long)qA * 128);
            const uint4* pb = (const uint4*)(qh + qBase + (long)qB * 128);
#pragma unroll
            for (int j = 0; j < 4; ++j) { unpack8(pa[j], &qa[j * 8]); unpack8(pb[j], &qb[j * 8]); }

            float accA[32], accB[32];
#pragma unroll
            for (int d = 0; d < 32; ++d) { accA[d] = 0.f; accB[d] = 0.f; }
            float mA = -1e30f, mB = -1e30f, lA = 0.f, lB = 0.f;

            for (int kt = 0; kt < 96; ++kt) {
                const float4* kr = (const float4*)&khs[kt][0];
                float sA = 0.f, sB = 0.f;
#pragma unroll
                for (int j = 0; j < 8; ++j) {
                    float4 kv = kr[j];
                    sA += qa[j*4+0]*kv.x + qa[j*4+1]*kv.y + qa[j*4+2]*kv.z + qa[j*4+3]*kv.w;
                    sB += qb[j*4+0]*kv.x + qb[j*4+1]*kv.y + qb[j*4+2]*kv.z + qb[j*4+3]*kv.w;
                }
                float mAn = fmaxf(mA, sA), mBn = fmaxf(mB, sB);
                float cA = __expf(mA - mAn), cB = __expf(mB - mBn);
                float pA = __expf(sA - mAn), pB = __expf(sB - mBn);
                lA = lA * cA + pA;
                lB = lB * cB + pB;
                const float4* vr = (const float4*)&vhs[kt][0];
#pragma unroll
                for (int j = 0; j < 8; ++j) {
                    float4 vv = vr[j];
                    accA[j*4+0] = accA[j*4+0]*cA + pA*vv.x;
                    accA[j*4+1] = accA[j*4+1]*cA + pA*vv.y;
                    accA[j*4+2] = accA[j*4+2]*cA + pA*vv.z;
                    accA[j*4+3] = accA[j*4+3]*cA + pA*vv.w;
                    accB[j*4+0] = accB[j*4+0]*cB + pB*vv.x;
                    accB[j*4+1] = accB[j*4+1]*cB + pB*vv.y;
                    accB[j*4+2] = accB[j*4+2]*cB + pB*vv.z;
                    accB[j*4+3] = accB[j*4+3]*cB + pB*vv.w;
                }
                mA = mAn; mB = mBn;
            }

            float invA = 1.f / (6.f * lA), invB = 1.f / (6.f * lB);
            int r = qA % 100;                        // qB has the same r (n differs by 3)
#pragma unroll
            for (int d = 0; d < 32; ++d)
                atomicAdd(&ams[r][d], accA[d] * invA + accB[d] * invB);
        }
    }
    __syncthreads();

    const long aBase = (long)bl * 12800 + m * 32;    // (bl*100)*128 + m*32
    for (int i = tid; i < 3200; i += 256) {
        int r = i >> 5, d = i & 31;
        am[aBase + r * 128 + d] = f2bf(ams[r][d]);
    }
}

// ---------- K3: output projection + bias + skip ----------
// 1 wave per block, 8 tokens per block; grid = 40000/8 = 5000.
__global__ __launch_bounds__(64) void out_proj_kernel(
    const unsigned short* __restrict__ am, const float* __restrict__ wp,
    const float* __restrict__ bp, const float* __restrict__ skip, float* __restrict__ out)
{
    const int lane = threadIdx.x;
    const int t0 = blockIdx.x * 8;

    float xlo[8], xhi[8];
#pragma unroll
    for (int t = 0; t < 8; ++t) {
        const unsigned short* p = am + (long)(t0 + t) * 128;
        xlo[t] = bf2f(p[lane]);
        xhi[t] = bf2f(p[64 + lane]);
    }

    float acc0[8], acc1[8];
    const float b0 = bp[lane], b1 = bp[64 + lane];
#pragma unroll
    for (int t = 0; t < 8; ++t) { acc0[t] = b0; acc1[t] = b1; }

    for (int k = 0; k < 64; ++k) {
        float w0 = wp[k * 128 + lane];
        float w1 = wp[k * 128 + 64 + lane];
#pragma unroll
        for (int t = 0; t < 8; ++t) {
            float xk = bcast_lane(xlo[t], k);
            acc0[t] = fmaf(xk, w0, acc0[t]);
            acc1[t] = fmaf(xk, w1, acc1[t]);
        }
    }
    for (int k = 0; k < 64; ++k) {
        float w0 = wp[(64 + k) * 128 + lane];
        float w1 = wp[(64 + k) * 128 + 64 + lane];
#pragma unroll
        for (int t = 0; t < 8; ++t) {
            float xk = bcast_lane(xhi[t], k);
            acc0[t] = fmaf(xk, w0, acc0[t]);
            acc1[t] = fmaf(xk, w1, acc1[t]);
        }
    }

#pragma unroll
    for (int t = 0; t < 8; ++t) {
        long o = (long)(t0 + t) * 128;
        out[o + lane]      = acc0[t] + skip[o + lane];
        out[o + 64 + lane] = acc1[t] + skip[o + 64 + lane];
    }
}

// ---------- launch ----------
extern "C" void kernel_launch(void* const* d_in, const int* in_sizes, int n_in,
                              void* d_out, int out_size, void* d_ws, size_t ws_size,
                              hipStream_t stream) {
    const float* q        = (const float*)d_in[0];
    const float* k        = (const float*)d_in[1];
    const float* v        = (const float*)d_in[2];
    const float* skip     = (const float*)d_in[3];
    const float* head_gate= (const float*)d_in[4];
    const float* ln_q_g   = (const float*)d_in[5];
    const float* ln_q_b   = (const float*)d_in[6];
    const float* ln_k_g   = (const float*)d_in[7];
    const float* ln_k_b   = (const float*)d_in[8];
    const float* ln_v_g   = (const float*)d_in[9];
    const float* ln_v_b   = (const float*)d_in[10];
    const float* wq       = (const float*)d_in[11];
    const float* bq       = (const float*)d_in[12];
    const float* wk       = (const float*)d_in[13];
    const float* bk       = (const float*)d_in[14];
    const float* wv       = (const float*)d_in[15];
    const float* bv       = (const float*)d_in[16];
    const float* wp       = (const float*)d_in[17];
    const float* bp       = (const float*)d_in[18];
    float* out = (float*)d_out;

    char* ws = (char*)d_ws;
    unsigned short* qh = (unsigned short*)(ws);               // 240000*128 bf16 = 61,440,000 B
    unsigned short* kh = (unsigned short*)(ws + 61440000);    //  38400*128 bf16 =  9,830,400 B
    unsigned short* vh = (unsigned short*)(ws + 71270400);    //  38400*128 bf16 =  9,830,400 B
    unsigned short* am = (unsigned short*)(ws + 81100800);    //  40000*128 bf16 = 10,240,000 B

    ln_proj_kernel<<<30000, 64, 0, stream>>>(q, ln_q_g, ln_q_b, wq, bq, head_gate, qh, 1);
    ln_proj_kernel<<<4800, 64, 0, stream>>>(k, ln_k_g, ln_k_b, wk, bk, head_gate, kh, 0);
    ln_proj_kernel<<<4800, 64, 0, stream>>>(v, ln_v_g, ln_v_b, wv, bv, head_gate, vh, 0);
    attn_kernel<<<1600, 256, 0, stream>>>(qh, kh, vh, am);
    out_proj_kernel<<<5000, 64, 0, stream>>>(am, wp, bp, skip, out);
}

// Round 2
// 510.158 us; speedup vs baseline: 1.4567x; 1.4567x over previous
//
#include <hip/hip_runtime.h>
#include <hip/hip_bf16.h>

#define DEV __device__ __forceinline__

typedef __attribute__((ext_vector_type(8))) short short8;
typedef __attribute__((ext_vector_type(4))) float f32x4;

// ---------- helpers ----------
DEV float wave_sum(float v) {
#pragma unroll
    for (int off = 1; off < 64; off <<= 1) v += __shfl_xor(v, off, 64);
    return v;
}
DEV float bcast_lane(float v, int srcLane) {
    return __uint_as_float(__builtin_amdgcn_readlane(__float_as_uint(v), srcLane));
}
DEV float bf2f(unsigned short h) { return __uint_as_float(((unsigned)h) << 16); }
DEV unsigned short f2bf(float f) {
    unsigned u = __float_as_uint(f);
    unsigned r = u + 0x7fffu + ((u >> 16) & 1u);
    return (unsigned short)(r >> 16);
}

// ---------- K1: LN + 128x128 projection (q or k/v), bf16 output ----------
// 1 wave per block, 8 tokens per block. Grid must be nTokens/8 (exact).
__global__ __launch_bounds__(64) void ln_proj_kernel(
    const float* __restrict__ src, const float* __restrict__ ln_g, const float* __restrict__ ln_b,
    const float* __restrict__ W, const float* __restrict__ bias,
    const float* __restrict__ head_gate, unsigned short* __restrict__ dst, int isQ)
{
    const int lane = threadIdx.x;
    const int t0 = blockIdx.x * 8;

    float xlo[8], xhi[8];
#pragma unroll
    for (int t = 0; t < 8; ++t) {
        int tok = t0 + t;
        int so;
        if (isQ) {
            int b = tok / 60000, rem = tok % 60000;
            int l = rem / 600, qn = rem % 600;
            int Xi = l / 10, Yi = l % 10;
            int nn = qn / 100, wA = (qn / 10) % 10, wB = qn % 10;
            so = ((((b * 6 + nn) * 10 + Xi) * 10 + Yi) * 10 + wA) * 10 + wB;
        } else {
            int b = tok / 9600, rem = tok % 9600;
            int l = rem / 96, kn = rem % 96;
            int Xi = l / 10, Yi = l % 10;
            int nn = kn / 16, wA = (kn / 4) % 4, wB = kn % 4;
            so = ((((b * 6 + nn) * 10 + Xi) * 10 + Yi) * 4 + wA) * 4 + wB;
        }
        const float* p = src + (long)so * 128;
        xlo[t] = p[lane];
        xhi[t] = p[64 + lane];
    }

    const float g0 = ln_g[lane], g1 = ln_g[64 + lane];
    const float e0 = ln_b[lane], e1 = ln_b[64 + lane];
#pragma unroll
    for (int t = 0; t < 8; ++t) {
        float s  = wave_sum(xlo[t] + xhi[t]);
        float s2 = wave_sum(xlo[t] * xlo[t] + xhi[t] * xhi[t]);
        float mean = s * (1.f / 128.f);
        float var  = s2 * (1.f / 128.f) - mean * mean;
        float rs = rsqrtf(var + 1e-5f);
        xlo[t] = (xlo[t] - mean) * rs * g0 + e0;
        xhi[t] = (xhi[t] - mean) * rs * g1 + e1;
    }

    float acc0[8], acc1[8];
    const float b0 = bias[lane], b1 = bias[64 + lane];
#pragma unroll
    for (int t = 0; t < 8; ++t) { acc0[t] = b0; acc1[t] = b1; }

    for (int k = 0; k < 64; ++k) {
        float w0 = W[k * 128 + lane];
        float w1 = W[k * 128 + 64 + lane];
#pragma unroll
        for (int t = 0; t < 8; ++t) {
            float xk = bcast_lane(xlo[t], k);
            acc0[t] = fmaf(xk, w0, acc0[t]);
            acc1[t] = fmaf(xk, w1, acc1[t]);
        }
    }
    for (int k = 0; k < 64; ++k) {
        float w0 = W[(64 + k) * 128 + lane];
        float w1 = W[(64 + k) * 128 + 64 + lane];
#pragma unroll
        for (int t = 0; t < 8; ++t) {
            float xk = bcast_lane(xhi[t], k);
            acc0[t] = fmaf(xk, w0, acc0[t]);
            acc1[t] = fmaf(xk, w1, acc1[t]);
        }
    }

    if (isQ) {
        const float scale = 0.17677669529663687f; // 32^-0.5
        float sg0 = scale * head_gate[lane >> 5];
        float sg1 = scale * head_gate[2 + (lane >> 5)];
#pragma unroll
        for (int t = 0; t < 8; ++t) { acc0[t] *= sg0; acc1[t] *= sg1; }
    }

#pragma unroll
    for (int t = 0; t < 8; ++t) {
        long o = (long)(t0 + t) * 128;
        dst[o + lane] = f2bf(acc0[t]);
        dst[o + 64 + lane] = f2bf(acc1[t]);
    }
}

// ---------- K2: MFMA windowed attention per (b,l,head); accumulates mean over n ----------
// grid = 400*4 = 1600 blocks of 256 threads (4 waves). qh/kh/vh bf16, out am bf16.
//
// Per block: Q (600x32), K (96x32), V (96x32) for one head slice.
// Swapped QK^T: D[kt][q] = mfma(A=K, B=Q^T). C/D layout: col=lane&15, row=(lane>>4)*4+reg.
// Softmax over kt lives on lanes {q, q+16, q+32, q+48} -> 2 shfl_xor.
// P round-trips LDS (so both PV operands use a consistent assumed k-slot map).
// PV: D[d][q] = mfma(A=V^T, B=P^T). 1/(6*softmax_sum) folded into P.
__global__ __launch_bounds__(256) void attn_mfma_kernel(
    const unsigned short* __restrict__ qh, const unsigned short* __restrict__ kh,
    const unsigned short* __restrict__ vh, unsigned short* __restrict__ am)
{
    __shared__ unsigned short Vt[32 * 104];      // V^T, row stride 104 (bank-spread)
    __shared__ unsigned short Pt[4][16 * 104];   // per-wave P^T tile [q][kt]
    __shared__ float ams[100 * 33];              // padded mean accumulator

    const int tid = threadIdx.x;
    const int m  = blockIdx.x & 3;
    const int bl = blockIdx.x >> 2;
    const int w = tid >> 6, lane = tid & 63;
    const int q15 = lane & 15, h = lane >> 4;

    const long kvBase = (long)bl * 12288 + m * 32;   // (bl*96)*128 + m*32
    const long qBase  = (long)bl * 76800 + m * 32;   // (bl*600)*128 + m*32
    const long aBase  = (long)bl * 12800 + m * 32;   // (bl*100)*128 + m*32

    for (int i = tid; i < 3300; i += 256) ams[i] = 0.f;

    // build V^T in LDS: Vt[d][kt] = V[kt][d]
    {
        const int d = tid & 31, kt0 = tid >> 5;
#pragma unroll
        for (int j = 0; j < 12; ++j) {
            int kt = kt0 + 8 * j;
            Vt[d * 104 + kt] = vh[kvBase + kt * 128 + d];
        }
    }

    // K A-fragments from global (held in regs, reused by all M-tiles)
    short8 kf[6];
#pragma unroll
    for (int nt = 0; nt < 6; ++nt)
        kf[nt] = *(const short8*)(kh + kvBase + (long)(nt * 16 + q15) * 128 + h * 8);

    __syncthreads();

    // V^T A-fragments from LDS (regs)
    short8 vf[2][3];
#pragma unroll
    for (int dt = 0; dt < 2; ++dt)
#pragma unroll
        for (int ks = 0; ks < 3; ++ks)
            vf[dt][ks] = *(const short8*)(Vt + (dt * 16 + q15) * 104 + ks * 32 + h * 8);

    unsigned short* ptw = Pt[w];

    for (int mt = w; mt < 38; mt += 4) {
        const int tok = mt * 16 + q15;
        const int tokc = tok < 600 ? tok : 599;

        short8 qf = *(const short8*)(qh + qBase + (long)tokc * 128 + h * 8);

        f32x4 s[6];
#pragma unroll
        for (int nt = 0; nt < 6; ++nt)
            s[nt] = __builtin_amdgcn_mfma_f32_16x16x32_bf16(kf[nt], qf, (f32x4){0.f, 0.f, 0.f, 0.f}, 0, 0, 0);

        // softmax over the 96 kt for this lane's q-column
        float mx = -3.0e38f;
#pragma unroll
        for (int nt = 0; nt < 6; ++nt)
#pragma unroll
            for (int r = 0; r < 4; ++r) mx = fmaxf(mx, s[nt][r]);
        mx = fmaxf(mx, __shfl_xor(mx, 16));
        mx = fmaxf(mx, __shfl_xor(mx, 32));

        float p[6][4];
        float sum = 0.f;
#pragma unroll
        for (int nt = 0; nt < 6; ++nt)
#pragma unroll
            for (int r = 0; r < 4; ++r) {
                p[nt][r] = __expf(s[nt][r] - mx);
                sum += p[nt][r];
            }
        sum += __shfl_xor(sum, 16);
        sum += __shfl_xor(sum, 32);
        const float inv = 1.f / (6.f * sum);   // softmax denom * mean over n

        // P^T (scaled) -> LDS: Pt[q][kt], kt = nt*16 + h*4 + r
#pragma unroll
        for (int nt = 0; nt < 6; ++nt) {
            ushort4 pk;
            pk.x = f2bf(p[nt][0] * inv);
            pk.y = f2bf(p[nt][1] * inv);
            pk.z = f2bf(p[nt][2] * inv);
            pk.w = f2bf(p[nt][3] * inv);
            *(ushort4*)(ptw + q15 * 104 + nt * 16 + h * 4) = pk;
        }
        asm volatile("s_waitcnt lgkmcnt(0)" ::: "memory");

        // PV: D[d][q] += V^T * P^T
        f32x4 o0 = {0.f, 0.f, 0.f, 0.f}, o1 = {0.f, 0.f, 0.f, 0.f};
#pragma unroll
        for (int ks = 0; ks < 3; ++ks) {
            short8 pf = *(const short8*)(ptw + q15 * 104 + ks * 32 + h * 8);
            o0 = __builtin_amdgcn_mfma_f32_16x16x32_bf16(vf[0][ks], pf, o0, 0, 0, 0);
            o1 = __builtin_amdgcn_mfma_f32_16x16x32_bf16(vf[1][ks], pf, o1, 0, 0, 0);
        }

        if (tok < 600) {
            const int r = tok % 100;
#pragma unroll
            for (int reg = 0; reg < 4; ++reg) {
                atomicAdd(&ams[r * 33 + h * 4 + reg],      o0[reg]);
                atomicAdd(&ams[r * 33 + 16 + h * 4 + reg], o1[reg]);
            }
        }
        asm volatile("s_waitcnt lgkmcnt(0)" ::: "memory");
    }

    __syncthreads();

    for (int i = tid; i < 3200; i += 256) {
        int r = i >> 5, d = i & 31;
        am[aBase + r * 128 + d] = f2bf(ams[r * 33 + d]);
    }
}

// ---------- K3: output projection + bias + skip ----------
// 1 wave per block, 8 tokens per block; grid = 40000/8 = 5000.
__global__ __launch_bounds__(64) void out_proj_kernel(
    const unsigned short* __restrict__ am, const float* __restrict__ wp,
    const float* __restrict__ bp, const float* __restrict__ skip, float* __restrict__ out)
{
    const int lane = threadIdx.x;
    const int t0 = blockIdx.x * 8;

    float xlo[8], xhi[8];
#pragma unroll
    for (int t = 0; t < 8; ++t) {
        const unsigned short* p = am + (long)(t0 + t) * 128;
        xlo[t] = bf2f(p[lane]);
        xhi[t] = bf2f(p[64 + lane]);
    }

    float acc0[8], acc1[8];
    const float b0 = bp[lane], b1 = bp[64 + lane];
#pragma unroll
    for (int t = 0; t < 8; ++t) { acc0[t] = b0; acc1[t] = b1; }

    for (int k = 0; k < 64; ++k) {
        float w0 = wp[k * 128 + lane];
        float w1 = wp[k * 128 + 64 + lane];
#pragma unroll
        for (int t = 0; t < 8; ++t) {
            float xk = bcast_lane(xlo[t], k);
            acc0[t] = fmaf(xk, w0, acc0[t]);
            acc1[t] = fmaf(xk, w1, acc1[t]);
        }
    }
    for (int k = 0; k < 64; ++k) {
        float w0 = wp[(64 + k) * 128 + lane];
        float w1 = wp[(64 + k) * 128 + 64 + lane];
#pragma unroll
        for (int t = 0; t < 8; ++t) {
            float xk = bcast_lane(xhi[t], k);
            acc0[t] = fmaf(xk, w0, acc0[t]);
            acc1[t] = fmaf(xk, w1, acc1[t]);
        }
    }

#pragma unroll
    for (int t = 0; t < 8; ++t) {
        long o = (long)(t0 + t) * 128;
        out[o + lane]      = acc0[t] + skip[o + lane];
        out[o + 64 + lane] = acc1[t] + skip[o + 64 + lane];
    }
}

// ---------- launch ----------
extern "C" void kernel_launch(void* const* d_in, const int* in_sizes, int n_in,
                              void* d_out, int out_size, void* d_ws, size_t ws_size,
                              hipStream_t stream) {
    const float* q        = (const float*)d_in[0];
    const float* k        = (const float*)d_in[1];
    const float* v        = (const float*)d_in[2];
    const float* skip     = (const float*)d_in[3];
    const float* head_gate= (const float*)d_in[4];
    const float* ln_q_g   = (const float*)d_in[5];
    const float* ln_q_b   = (const float*)d_in[6];
    const float* ln_k_g   = (const float*)d_in[7];
    const float* ln_k_b   = (const float*)d_in[8];
    const float* ln_v_g   = (const float*)d_in[9];
    const float* ln_v_b   = (const float*)d_in[10];
    const float* wq       = (const float*)d_in[11];
    const float* bq       = (const float*)d_in[12];
    const float* wk       = (const float*)d_in[13];
    const float* bk       = (const float*)d_in[14];
    const float* wv       = (const float*)d_in[15];
    const float* bv       = (const float*)d_in[16];
    const float* wp       = (const float*)d_in[17];
    const float* bp       = (const float*)d_in[18];
    float* out = (float*)d_out;

    char* ws = (char*)d_ws;
    unsigned short* qh = (unsigned short*)(ws);               // 240000*128 bf16
    unsigned short* kh = (unsigned short*)(ws + 61440000);    //  38400*128 bf16
    unsigned short* vh = (unsigned short*)(ws + 71270400);    //  38400*128 bf16
    unsigned short* am = (unsigned short*)(ws + 81100800);    //  40000*128 bf16

    ln_proj_kernel<<<30000, 64, 0, stream>>>(q, ln_q_g, ln_q_b, wq, bq, head_gate, qh, 1);
    ln_proj_kernel<<<4800, 64, 0, stream>>>(k, ln_k_g, ln_k_b, wk, bk, head_gate, kh, 0);
    ln_proj_kernel<<<4800, 64, 0, stream>>>(v, ln_v_g, ln_v_b, wv, bv, head_gate, vh, 0);
    attn_mfma_kernel<<<1600, 256, 0, stream>>>(qh, kh, vh, am);
    out_proj_kernel<<<5000, 64, 0, stream>>>(am, wp, bp, skip, out);
}